// Round 1
// baseline (1913.161 us; speedup 1.0000x reference)
//
#include <hip/hip_runtime.h>
#include <hip/hip_bf16.h>

#define N_NODES 50000
#define IN_C    96
#define HID_C   128
#define OUT_C   64

// ---------------------------------------------------------------------------
// Scatter layer 1: agg_x[dst] += x[src] (96 f32/edge, float4 loads, 4 HW
// atomics per thread), plus deg[dst] += 1 from the c==0 lane group.
// ---------------------------------------------------------------------------
__global__ __launch_bounds__(256) void scatter1_kernel(
    const int* __restrict__ src, const int* __restrict__ dst,
    const float* __restrict__ x, float* __restrict__ aggx,
    float* __restrict__ deg, int E)
{
    int idx = blockIdx.x * 256 + threadIdx.x;          // E*24 work items
    int total = E * 24;
    if (idx >= total) return;
    int e = idx / 24;
    int c = idx - e * 24;                               // float4 index in row
    int s = src[e];
    int d = dst[e];
    float4 v = ((const float4*)x)[(size_t)s * 24 + c];
    float* base = aggx + (size_t)d * IN_C + c * 4;
    unsafeAtomicAdd(base + 0, v.x);
    unsafeAtomicAdd(base + 1, v.y);
    unsafeAtomicAdd(base + 2, v.z);
    unsafeAtomicAdd(base + 3, v.w);
    if (c == 0) unsafeAtomicAdd(deg + d, 1.0f);
}

// ---------------------------------------------------------------------------
// GEMM1 fused: h = relu( (aggx/deg) @ w1_l + x @ w1_r + b1 )   [50000 x 128]
// 16 rows/block, 256 threads: col = t&127, row-group = t>>7 (8 rows each).
// ---------------------------------------------------------------------------
__global__ __launch_bounds__(256) void gemm1_kernel(
    const float* __restrict__ x, const float* __restrict__ aggx,
    const float* __restrict__ deg,
    const float* __restrict__ w_l, const float* __restrict__ w_r,
    const float* __restrict__ b1, float* __restrict__ h)
{
    __shared__ float As[16][IN_C];    // x tile
    __shared__ float Bs[16][IN_C];    // aggx * inv_deg tile
    __shared__ float invd[16];

    int row0 = blockIdx.x * 16;
    int t = threadIdx.x;
    if (t < 16) invd[t] = 1.0f / fmaxf(deg[row0 + t], 1.0f);
    __syncthreads();

    const float4* x4 = (const float4*)x;
    const float4* a4 = (const float4*)aggx;
    for (int i = t; i < 16 * 24; i += 256) {          // 384 float4 per matrix
        int r = i / 24, c = i - r * 24;
        size_t g = (size_t)(row0 + r) * 24 + c;
        ((float4*)&As[r][c * 4])[0] = x4[g];
        float4 w = a4[g];
        float sfac = invd[r];
        w.x *= sfac; w.y *= sfac; w.z *= sfac; w.w *= sfac;
        ((float4*)&Bs[r][c * 4])[0] = w;
    }
    __syncthreads();

    int col = t & 127;
    int rg  = t >> 7;                                  // 0..1
    float acc[8];
#pragma unroll
    for (int rr = 0; rr < 8; rr++) acc[rr] = 0.0f;

    for (int k = 0; k < IN_C; k++) {
        float wl = w_l[k * HID_C + col];
        float wr = w_r[k * HID_C + col];
#pragma unroll
        for (int rr = 0; rr < 8; rr++) {
            int r = rg * 8 + rr;
            acc[rr] = fmaf(Bs[r][k], wl, acc[rr]);
            acc[rr] = fmaf(As[r][k], wr, acc[rr]);
        }
    }
    float bias = b1[col];
#pragma unroll
    for (int rr = 0; rr < 8; rr++) {
        int r = rg * 8 + rr;
        float v = acc[rr] + bias;
        h[(size_t)(row0 + r) * HID_C + col] = fmaxf(v, 0.0f);
    }
}

// ---------------------------------------------------------------------------
// GEMM2 fused: p = h @ w2_l ; out(q) = h @ w2_r + b2     [50000 x 64] each
// 16 rows/block, 256 threads: col = t&63, row-group = t>>6 (4 rows each).
// ---------------------------------------------------------------------------
__global__ __launch_bounds__(256) void gemm2_kernel(
    const float* __restrict__ h,
    const float* __restrict__ w_l, const float* __restrict__ w_r,
    const float* __restrict__ b2, float* __restrict__ p,
    float* __restrict__ out)
{
    __shared__ float Hs[16][HID_C];
    int row0 = blockIdx.x * 16;
    int t = threadIdx.x;
    const float4* h4 = (const float4*)h;
    for (int i = t; i < 16 * 32; i += 256) {          // 512 float4
        int r = i >> 5, c = i & 31;
        ((float4*)&Hs[r][c * 4])[0] = h4[(size_t)(row0 + r) * 32 + c];
    }
    __syncthreads();

    int col = t & 63;
    int rg  = t >> 6;                                  // 0..3
    float accp[4], accq[4];
#pragma unroll
    for (int rr = 0; rr < 4; rr++) { accp[rr] = 0.0f; accq[rr] = 0.0f; }

    for (int k = 0; k < HID_C; k++) {
        float wl = w_l[k * OUT_C + col];
        float wr = w_r[k * OUT_C + col];
#pragma unroll
        for (int rr = 0; rr < 4; rr++) {
            float hv = Hs[rg * 4 + rr][k];
            accp[rr] = fmaf(hv, wl, accp[rr]);
            accq[rr] = fmaf(hv, wr, accq[rr]);
        }
    }
    float bias = b2[col];
#pragma unroll
    for (int rr = 0; rr < 4; rr++) {
        int r = rg * 4 + rr;
        size_t o = (size_t)(row0 + r) * OUT_C + col;
        p[o] = accp[rr];
        out[o] = accq[rr] + bias;
    }
}

// ---------------------------------------------------------------------------
// Scatter layer 2: aggp[dst] += p[src] (64 f32/edge).
// ---------------------------------------------------------------------------
__global__ __launch_bounds__(256) void scatter2_kernel(
    const int* __restrict__ src, const int* __restrict__ dst,
    const float* __restrict__ p, float* __restrict__ aggp, int E)
{
    int idx = blockIdx.x * 256 + threadIdx.x;          // E*16 work items
    int total = E * 16;
    if (idx >= total) return;
    int e = idx >> 4;
    int c = idx & 15;
    int s = src[e];
    int d = dst[e];
    float4 v = ((const float4*)p)[(size_t)s * 16 + c];
    float* base = aggp + (size_t)d * OUT_C + c * 4;
    unsafeAtomicAdd(base + 0, v.x);
    unsafeAtomicAdd(base + 1, v.y);
    unsafeAtomicAdd(base + 2, v.z);
    unsafeAtomicAdd(base + 3, v.w);
}

// ---------------------------------------------------------------------------
// Finalize: out += aggp * inv_deg  (row-wise), float4-vectorized.
// ---------------------------------------------------------------------------
__global__ __launch_bounds__(256) void finalize_kernel(
    const float* __restrict__ aggp, const float* __restrict__ deg,
    float* __restrict__ out)
{
    int idx = blockIdx.x * 256 + threadIdx.x;          // N * 16 work items
    int row = idx >> 4;
    float id = 1.0f / fmaxf(deg[row], 1.0f);
    float4 a = ((const float4*)aggp)[idx];
    float4 o = ((float4*)out)[idx];
    o.x = fmaf(a.x, id, o.x);
    o.y = fmaf(a.y, id, o.y);
    o.z = fmaf(a.z, id, o.z);
    o.w = fmaf(a.w, id, o.w);
    ((float4*)out)[idx] = o;
}

extern "C" void kernel_launch(void* const* d_in, const int* in_sizes, int n_in,
                              void* d_out, int out_size, void* d_ws, size_t ws_size,
                              hipStream_t stream)
{
    const float* x   = (const float*)d_in[0];
    const int*   ei  = (const int*)d_in[1];
    const float* w1l = (const float*)d_in[2];
    const float* w1r = (const float*)d_in[3];
    const float* b1  = (const float*)d_in[4];
    const float* w2l = (const float*)d_in[5];
    const float* w2r = (const float*)d_in[6];
    const float* b2  = (const float*)d_in[7];
    float* out = (float*)d_out;

    int E = in_sizes[1] / 2;                  // edge_index is [2, E]
    const int* src = ei;
    const int* dst = ei + E;

    // Workspace layout (floats). Zero-init region is contiguous at the front.
    float* ws   = (float*)d_ws;
    float* deg  = ws;                                   // 50000
    float* aggx = deg  + N_NODES;                       // 50000*96
    float* aggp = aggx + (size_t)N_NODES * IN_C;        // 50000*64
    float* h    = aggp + (size_t)N_NODES * OUT_C;       // 50000*128
    float* p    = h    + (size_t)N_NODES * HID_C;       // 50000*64

    size_t zero_bytes = ((size_t)N_NODES * (1 + IN_C + OUT_C)) * sizeof(float);
    hipMemsetAsync(deg, 0, zero_bytes, stream);

    int grid_s1 = (E * 24 + 255) / 256;
    scatter1_kernel<<<grid_s1, 256, 0, stream>>>(src, dst, x, aggx, deg, E);

    gemm1_kernel<<<N_NODES / 16, 256, 0, stream>>>(x, aggx, deg, w1l, w1r, b1, h);
    gemm2_kernel<<<N_NODES / 16, 256, 0, stream>>>(h, w2l, w2r, b2, p, out);

    int grid_s2 = (E * 16 + 255) / 256;
    scatter2_kernel<<<grid_s2, 256, 0, stream>>>(src, dst, p, aggp, E);

    finalize_kernel<<<(N_NODES * 16) / 256, 256, 0, stream>>>(aggp, deg, out);
}

// Round 2
// 392.363 us; speedup vs baseline: 4.8760x; 4.8760x over previous
//
#include <hip/hip_runtime.h>
#include <hip/hip_bf16.h>

#define N_NODES 50000
#define IN_C    96
#define HID_C   128
#define OUT_C   64
#define NPART   196   // ceil(50000/256)

// ---------------------------------------------------------------------------
// CSR build step 1: in-degree histogram (int atomics).
// ---------------------------------------------------------------------------
__global__ __launch_bounds__(256) void hist_kernel(
    const int* __restrict__ dst, int* __restrict__ cnt, int E)
{
    int e = blockIdx.x * 256 + threadIdx.x;
    if (e < E) atomicAdd(&cnt[dst[e]], 1);
}

// CSR build step 2a: per-256-chunk sums.
__global__ __launch_bounds__(256) void block_reduce_kernel(
    const int* __restrict__ cnt, int* __restrict__ part)
{
    __shared__ int buf[256];
    int t = threadIdx.x;
    int i = blockIdx.x * 256 + t;
    buf[t] = (i < N_NODES) ? cnt[i] : 0;
    __syncthreads();
    for (int off = 128; off > 0; off >>= 1) {
        if (t < off) buf[t] += buf[t + off];
        __syncthreads();
    }
    if (t == 0) part[blockIdx.x] = buf[0];
}

// CSR build step 2b: exclusive scan of the NPART partials (single block).
__global__ __launch_bounds__(256) void scan_partials_kernel(
    const int* __restrict__ part, int* __restrict__ partoff)
{
    __shared__ int buf[256];
    int t = threadIdx.x;
    int v0 = (t < NPART) ? part[t] : 0;
    buf[t] = v0;
    __syncthreads();
    for (int off = 1; off < 256; off <<= 1) {
        int v = (t >= off) ? buf[t - off] : 0;
        __syncthreads();
        buf[t] += v;
        __syncthreads();
    }
    if (t < NPART) partoff[t] = buf[t] - v0;   // exclusive
}

// CSR build step 2c: per-chunk exclusive scan + global offset; emit
// rowstart, cursor (mutable copy), and deg as float.
__global__ __launch_bounds__(256) void block_scan_kernel(
    const int* __restrict__ cnt, const int* __restrict__ partoff,
    int* __restrict__ rowstart, int* __restrict__ cursor,
    float* __restrict__ degf)
{
    __shared__ int buf[256];
    int t = threadIdx.x;
    int i = blockIdx.x * 256 + t;
    int c = (i < N_NODES) ? cnt[i] : 0;
    buf[t] = c;
    __syncthreads();
    for (int off = 1; off < 256; off <<= 1) {
        int v = (t >= off) ? buf[t - off] : 0;
        __syncthreads();
        buf[t] += v;
        __syncthreads();
    }
    if (i < N_NODES) {
        int excl = buf[t] - c + partoff[blockIdx.x];
        rowstart[i] = excl;
        cursor[i]   = excl;
        degf[i]     = (float)c;
    }
}

// CSR build step 3: scatter edge sources into adjacency buckets.
__global__ __launch_bounds__(256) void fill_kernel(
    const int* __restrict__ src, const int* __restrict__ dst,
    int* __restrict__ cursor, int* __restrict__ adj, int E)
{
    int e = blockIdx.x * 256 + threadIdx.x;
    if (e < E) {
        int d = dst[e];
        int pos = atomicAdd(&cursor[d], 1);
        adj[pos] = src[e];
    }
}

// ---------------------------------------------------------------------------
// Gather-aggregate layer 1: aggx[i] = sum_{j in N(i)} x[j]  (96 ch).
// Thread = (node, float4 column c in 0..23); register accumulation.
// ---------------------------------------------------------------------------
__global__ __launch_bounds__(256) void gather1_kernel(
    const int* __restrict__ rowstart, const int* __restrict__ cnt,
    const int* __restrict__ adj, const float* __restrict__ x,
    float* __restrict__ aggx)
{
    int idx = blockIdx.x * 256 + threadIdx.x;
    if (idx >= N_NODES * 24) return;
    int node = idx / 24;
    int c = idx - node * 24;
    int beg = rowstart[node];
    int end = beg + cnt[node];
    const float4* x4 = (const float4*)x;
    float4 acc = make_float4(0.f, 0.f, 0.f, 0.f);
    for (int j = beg; j < end; j++) {
        int s = adj[j];
        float4 v = x4[(size_t)s * 24 + c];
        acc.x += v.x; acc.y += v.y; acc.z += v.z; acc.w += v.w;
    }
    ((float4*)aggx)[(size_t)node * 24 + c] = acc;
}

// Gather-aggregate layer 2: aggp[i] = sum_{j in N(i)} p[j]  (64 ch).
__global__ __launch_bounds__(256) void gather2_kernel(
    const int* __restrict__ rowstart, const int* __restrict__ cnt,
    const int* __restrict__ adj, const float* __restrict__ p,
    float* __restrict__ aggp)
{
    int idx = blockIdx.x * 256 + threadIdx.x;   // N*16 exactly
    int node = idx >> 4;
    int c = idx & 15;
    int beg = rowstart[node];
    int end = beg + cnt[node];
    const float4* p4 = (const float4*)p;
    float4 acc = make_float4(0.f, 0.f, 0.f, 0.f);
    for (int j = beg; j < end; j++) {
        int s = adj[j];
        float4 v = p4[(size_t)s * 16 + c];
        acc.x += v.x; acc.y += v.y; acc.z += v.z; acc.w += v.w;
    }
    ((float4*)aggp)[(size_t)node * 16 + c] = acc;
}

// ---------------------------------------------------------------------------
// GEMM1 fused: h = relu( (aggx/deg) @ w1_l + x @ w1_r + b1 )   [50000 x 128]
// ---------------------------------------------------------------------------
__global__ __launch_bounds__(256) void gemm1_kernel(
    const float* __restrict__ x, const float* __restrict__ aggx,
    const float* __restrict__ deg,
    const float* __restrict__ w_l, const float* __restrict__ w_r,
    const float* __restrict__ b1, float* __restrict__ h)
{
    __shared__ float As[16][IN_C];    // x tile
    __shared__ float Bs[16][IN_C];    // aggx * inv_deg tile
    __shared__ float invd[16];

    int row0 = blockIdx.x * 16;
    int t = threadIdx.x;
    if (t < 16) invd[t] = 1.0f / fmaxf(deg[row0 + t], 1.0f);
    __syncthreads();

    const float4* x4 = (const float4*)x;
    const float4* a4 = (const float4*)aggx;
    for (int i = t; i < 16 * 24; i += 256) {
        int r = i / 24, c = i - r * 24;
        size_t g = (size_t)(row0 + r) * 24 + c;
        ((float4*)&As[r][c * 4])[0] = x4[g];
        float4 w = a4[g];
        float sfac = invd[r];
        w.x *= sfac; w.y *= sfac; w.z *= sfac; w.w *= sfac;
        ((float4*)&Bs[r][c * 4])[0] = w;
    }
    __syncthreads();

    int col = t & 127;
    int rg  = t >> 7;
    float acc[8];
#pragma unroll
    for (int rr = 0; rr < 8; rr++) acc[rr] = 0.0f;

    for (int k = 0; k < IN_C; k++) {
        float wl = w_l[k * HID_C + col];
        float wr = w_r[k * HID_C + col];
#pragma unroll
        for (int rr = 0; rr < 8; rr++) {
            int r = rg * 8 + rr;
            acc[rr] = fmaf(Bs[r][k], wl, acc[rr]);
            acc[rr] = fmaf(As[r][k], wr, acc[rr]);
        }
    }
    float bias = b1[col];
#pragma unroll
    for (int rr = 0; rr < 8; rr++) {
        int r = rg * 8 + rr;
        float v = acc[rr] + bias;
        h[(size_t)(row0 + r) * HID_C + col] = fmaxf(v, 0.0f);
    }
}

// ---------------------------------------------------------------------------
// GEMM2 fused: p = h @ w2_l ; out = h @ w2_r + b2     [50000 x 64] each
// ---------------------------------------------------------------------------
__global__ __launch_bounds__(256) void gemm2_kernel(
    const float* __restrict__ h,
    const float* __restrict__ w_l, const float* __restrict__ w_r,
    const float* __restrict__ b2, float* __restrict__ p,
    float* __restrict__ out)
{
    __shared__ float Hs[16][HID_C];
    int row0 = blockIdx.x * 16;
    int t = threadIdx.x;
    const float4* h4 = (const float4*)h;
    for (int i = t; i < 16 * 32; i += 256) {
        int r = i >> 5, c = i & 31;
        ((float4*)&Hs[r][c * 4])[0] = h4[(size_t)(row0 + r) * 32 + c];
    }
    __syncthreads();

    int col = t & 63;
    int rg  = t >> 6;
    float accp[4], accq[4];
#pragma unroll
    for (int rr = 0; rr < 4; rr++) { accp[rr] = 0.0f; accq[rr] = 0.0f; }

    for (int k = 0; k < HID_C; k++) {
        float wl = w_l[k * OUT_C + col];
        float wr = w_r[k * OUT_C + col];
#pragma unroll
        for (int rr = 0; rr < 4; rr++) {
            float hv = Hs[rg * 4 + rr][k];
            accp[rr] = fmaf(hv, wl, accp[rr]);
            accq[rr] = fmaf(hv, wr, accq[rr]);
        }
    }
    float bias = b2[col];
#pragma unroll
    for (int rr = 0; rr < 4; rr++) {
        int r = rg * 4 + rr;
        size_t o = (size_t)(row0 + r) * OUT_C + col;
        p[o] = accp[rr];
        out[o] = accq[rr] + bias;
    }
}

// ---------------------------------------------------------------------------
// Finalize: out += aggp * inv_deg  (row-wise), float4-vectorized.
// ---------------------------------------------------------------------------
__global__ __launch_bounds__(256) void finalize_kernel(
    const float* __restrict__ aggp, const float* __restrict__ deg,
    float* __restrict__ out)
{
    int idx = blockIdx.x * 256 + threadIdx.x;
    int row = idx >> 4;
    float id = 1.0f / fmaxf(deg[row], 1.0f);
    float4 a = ((const float4*)aggp)[idx];
    float4 o = ((float4*)out)[idx];
    o.x = fmaf(a.x, id, o.x);
    o.y = fmaf(a.y, id, o.y);
    o.z = fmaf(a.z, id, o.z);
    o.w = fmaf(a.w, id, o.w);
    ((float4*)out)[idx] = o;
}

extern "C" void kernel_launch(void* const* d_in, const int* in_sizes, int n_in,
                              void* d_out, int out_size, void* d_ws, size_t ws_size,
                              hipStream_t stream)
{
    const float* x   = (const float*)d_in[0];
    const int*   ei  = (const int*)d_in[1];
    const float* w1l = (const float*)d_in[2];
    const float* w1r = (const float*)d_in[3];
    const float* b1  = (const float*)d_in[4];
    const float* w2l = (const float*)d_in[5];
    const float* w2r = (const float*)d_in[6];
    const float* b2  = (const float*)d_in[7];
    float* out = (float*)d_out;

    int E = in_sizes[1] / 2;                  // edge_index is [2, E]
    const int* src = ei;
    const int* dst = ei + E;

    // Workspace layout (4B elements). Aliasing: p reuses aggx (aggx dead
    // after gemm1); aggp reuses h (h dead after gemm2).
    int*   cnt      = (int*)d_ws;                      // 50000
    int*   rowstart = cnt + N_NODES;                   // 50000
    int*   cursor   = rowstart + N_NODES;              // 50000
    int*   part     = cursor + N_NODES;                // 256
    int*   partoff  = part + 256;                      // 256
    int*   adj      = partoff + 256;                   // E (800000)
    float* degf     = (float*)(adj + E);               // 50000
    float* aggx     = degf + N_NODES;                  // 50000*96
    float* h        = aggx + (size_t)N_NODES * IN_C;   // 50000*128
    float* p        = aggx;                            // alias (<= aggx size)
    float* aggp     = h;                               // alias (<= h size)

    hipMemsetAsync(cnt, 0, N_NODES * sizeof(int), stream);

    int grid_e = (E + 255) / 256;
    hist_kernel<<<grid_e, 256, 0, stream>>>(dst, cnt, E);
    block_reduce_kernel<<<NPART, 256, 0, stream>>>(cnt, part);
    scan_partials_kernel<<<1, 256, 0, stream>>>(part, partoff);
    block_scan_kernel<<<NPART, 256, 0, stream>>>(cnt, partoff, rowstart, cursor, degf);
    fill_kernel<<<grid_e, 256, 0, stream>>>(src, dst, cursor, adj, E);

    gather1_kernel<<<(N_NODES * 24 + 255) / 256, 256, 0, stream>>>(
        rowstart, cnt, adj, x, aggx);
    gemm1_kernel<<<N_NODES / 16, 256, 0, stream>>>(x, aggx, degf, w1l, w1r, b1, h);
    gemm2_kernel<<<N_NODES / 16, 256, 0, stream>>>(h, w2l, w2r, b2, p, out);
    gather2_kernel<<<(N_NODES * 16) / 256, 256, 0, stream>>>(
        rowstart, cnt, adj, p, aggp);
    finalize_kernel<<<(N_NODES * 16) / 256, 256, 0, stream>>>(aggp, degf, out);
}

// Round 3
// 277.114 us; speedup vs baseline: 6.9039x; 1.4159x over previous
//
#include <hip/hip_runtime.h>
#include <hip/hip_bf16.h>

#define N_NODES 50000
#define IN_C    96
#define HID_C   128
#define OUT_C   64
#define NPART   196   // ceil(50000/256)
#define MROWS   50016 // 32-row-tile padded M

typedef __attribute__((ext_vector_type(8))) short short8;  // 8 bf16 (4 VGPR)
typedef __attribute__((ext_vector_type(4))) float f32x4;

// round-to-nearest-even fp32 -> bf16 bits
__device__ inline unsigned int f2bf(float f) {
    unsigned int u = __float_as_uint(f);
    return (u + 0x7fffu + ((u >> 16) & 1u)) >> 16;
}
__device__ inline unsigned int pack2(float lo, float hi) {
    return f2bf(lo) | (f2bf(hi) << 16);
}
__device__ inline float blo(unsigned int u) { return __uint_as_float(u << 16); }
__device__ inline float bhi(unsigned int u) { return __uint_as_float(u & 0xffff0000u); }

// ---------------------------------------------------------------------------
// CSR build
// ---------------------------------------------------------------------------
__global__ __launch_bounds__(256) void hist_kernel(
    const int* __restrict__ dst, int* __restrict__ cnt, int E)
{
    int e = blockIdx.x * 256 + threadIdx.x;
    if (e < E) atomicAdd(&cnt[dst[e]], 1);
}

__global__ __launch_bounds__(256) void block_reduce_kernel(
    const int* __restrict__ cnt, int* __restrict__ part)
{
    __shared__ int buf[256];
    int t = threadIdx.x;
    int i = blockIdx.x * 256 + t;
    buf[t] = (i < N_NODES) ? cnt[i] : 0;
    __syncthreads();
    for (int off = 128; off > 0; off >>= 1) {
        if (t < off) buf[t] += buf[t + off];
        __syncthreads();
    }
    if (t == 0) part[blockIdx.x] = buf[0];
}

__global__ __launch_bounds__(256) void scan_partials_kernel(
    const int* __restrict__ part, int* __restrict__ partoff)
{
    __shared__ int buf[256];
    int t = threadIdx.x;
    int v0 = (t < NPART) ? part[t] : 0;
    buf[t] = v0;
    __syncthreads();
    for (int off = 1; off < 256; off <<= 1) {
        int v = (t >= off) ? buf[t - off] : 0;
        __syncthreads();
        buf[t] += v;
        __syncthreads();
    }
    if (t < NPART) partoff[t] = buf[t] - v0;   // exclusive
}

__global__ __launch_bounds__(256) void block_scan_kernel(
    const int* __restrict__ cnt, const int* __restrict__ partoff,
    int* __restrict__ rowstart, int* __restrict__ cursor)
{
    __shared__ int buf[256];
    int t = threadIdx.x;
    int i = blockIdx.x * 256 + t;
    int c = (i < N_NODES) ? cnt[i] : 0;
    buf[t] = c;
    __syncthreads();
    for (int off = 1; off < 256; off <<= 1) {
        int v = (t >= off) ? buf[t - off] : 0;
        __syncthreads();
        buf[t] += v;
        __syncthreads();
    }
    if (i < N_NODES) {
        int excl = buf[t] - c + partoff[blockIdx.x];
        rowstart[i] = excl;
        cursor[i]   = excl;
    }
}

__global__ __launch_bounds__(256) void fill_kernel(
    const int* __restrict__ src, const int* __restrict__ dst,
    int* __restrict__ cursor, int* __restrict__ adj, int E)
{
    int e = blockIdx.x * 256 + threadIdx.x;
    if (e < E) {
        int d = dst[e];
        int pos = atomicAdd(&cursor[d], 1);
        adj[pos] = src[e];
    }
}

// ---------------------------------------------------------------------------
// Converters (fp32 -> bf16)
// ---------------------------------------------------------------------------
// x[50000][96] f32 -> xb[50000][96] bf16 and A1[n][96..191] (x half).
__global__ __launch_bounds__(256) void conv_x_kernel(
    const float* __restrict__ x, uint4* __restrict__ xb4,
    uint4* __restrict__ a14)
{
    int idx = blockIdx.x * 256 + threadIdx.x;     // N*12
    if (idx >= N_NODES * 12) return;
    int node = idx / 12;
    int c = idx - node * 12;
    const float4* x4 = (const float4*)x;
    float4 u = x4[(size_t)node * 24 + 2 * c];
    float4 v = x4[(size_t)node * 24 + 2 * c + 1];
    uint4 w;
    w.x = pack2(u.x, u.y); w.y = pack2(u.z, u.w);
    w.z = pack2(v.x, v.y); w.w = pack2(v.z, v.w);
    xb4[(size_t)node * 12 + c] = w;
    a14[(size_t)node * 24 + 12 + c] = w;
}

// W1t[128][192] bf16: W1t[col][k] = k<96 ? w1l[k][col] : w1r[k-96][col]
__global__ __launch_bounds__(256) void conv_w1_kernel(
    const float* __restrict__ w1l, const float* __restrict__ w1r,
    unsigned short* __restrict__ wt)
{
    int i = blockIdx.x * 256 + threadIdx.x;       // 128*192
    if (i >= 128 * 192) return;
    int col = i / 192, k = i - col * 192;
    float v = (k < 96) ? w1l[k * 128 + col] : w1r[(k - 96) * 128 + col];
    wt[i] = (unsigned short)f2bf(v);
}

// W2t[128][128] bf16: W2t[col][k] = col<64 ? w2l[k][col] : w2r[k][col-64]
__global__ __launch_bounds__(256) void conv_w2_kernel(
    const float* __restrict__ w2l, const float* __restrict__ w2r,
    unsigned short* __restrict__ wt)
{
    int i = blockIdx.x * 256 + threadIdx.x;       // 128*128
    if (i >= 128 * 128) return;
    int col = i / 128, k = i - col * 128;
    float v = (col < 64) ? w2l[k * 64 + col] : w2r[k * 64 + col - 64];
    wt[i] = (unsigned short)f2bf(v);
}

// ---------------------------------------------------------------------------
// Gather 1: A1[n][0..95] = (sum_{j in N(n)} xb[j]) / deg(n)   (bf16 out)
// thread = (node, 8-ch chunk c in 0..11); fp32 register accumulation.
// ---------------------------------------------------------------------------
__global__ __launch_bounds__(256) void gather1_kernel(
    const int* __restrict__ rowstart, const int* __restrict__ cnt,
    const int* __restrict__ adj, const uint4* __restrict__ xb4,
    uint4* __restrict__ a14)
{
    int idx = blockIdx.x * 256 + threadIdx.x;
    if (idx >= N_NODES * 12) return;
    int node = idx / 12;
    int c = idx - node * 12;
    int beg = rowstart[node];
    int d = cnt[node];
    int end = beg + d;
    float a0=0,a1=0,a2=0,a3=0,a4=0,a5=0,a6=0,a7=0;
    for (int j = beg; j < end; j++) {
        int s = adj[j];
        uint4 v = xb4[(size_t)s * 12 + c];
        a0 += blo(v.x); a1 += bhi(v.x);
        a2 += blo(v.y); a3 += bhi(v.y);
        a4 += blo(v.z); a5 += bhi(v.z);
        a6 += blo(v.w); a7 += bhi(v.w);
    }
    float id = 1.0f / (float)max(d, 1);
    uint4 w;
    w.x = pack2(a0 * id, a1 * id); w.y = pack2(a2 * id, a3 * id);
    w.z = pack2(a4 * id, a5 * id); w.w = pack2(a6 * id, a7 * id);
    a14[(size_t)node * 24 + c] = w;
}

// ---------------------------------------------------------------------------
// GEMM1 (bf16 MFMA): h = relu(A1 @ W1t^T + b1)  [50000 x 128], h bf16.
// Block: 32 rows x 128 cols, 4 waves; wave = 32-col slab; 2x2 16x16 tiles.
// ---------------------------------------------------------------------------
__global__ __launch_bounds__(256) void gemm1_mfma(
    const uint4* __restrict__ a14, const uint4* __restrict__ w4,
    const float* __restrict__ b1, unsigned short* __restrict__ h)
{
    constexpr int KD = 192, KP = KD + 8;          // padded bf16 stride (200)
    __shared__ unsigned short lw[128 * KP];       // 51200 B
    __shared__ unsigned short la[32 * KP];        // 12800 B
    int t = threadIdx.x;
    uint4* lw4 = (uint4*)lw;
    uint4* la4 = (uint4*)la;
    // stage whole W1t (128 x 24 uint4) and A-tile (32 x 24 uint4)
    for (int i = t; i < 128 * 24; i += 256) {
        int r = i / 24, c = i - r * 24;
        lw4[r * 25 + c] = w4[i];
    }
    int row0 = blockIdx.x * 32;
    for (int i = t; i < 32 * 24; i += 256) {
        int r = i / 24, c = i - r * 24;
        la4[r * 25 + c] = a14[(size_t)(row0 + r) * 24 + c];
    }
    __syncthreads();

    int wave = t >> 6, lane = t & 63;
    int m = lane & 15, half = lane >> 4;          // 0..3
    int koff = half * 8;
    f32x4 acc00 = {}, acc01 = {}, acc10 = {}, acc11 = {};
#pragma unroll
    for (int k0 = 0; k0 < KD; k0 += 32) {
        short8 A0 = *(const short8*)&la[(m)      * KP + k0 + koff];
        short8 A1 = *(const short8*)&la[(16 + m) * KP + k0 + koff];
        short8 B0 = *(const short8*)&lw[(wave * 32 + m)      * KP + k0 + koff];
        short8 B1 = *(const short8*)&lw[(wave * 32 + 16 + m) * KP + k0 + koff];
        acc00 = __builtin_amdgcn_mfma_f32_16x16x32_bf16(A0, B0, acc00, 0, 0, 0);
        acc01 = __builtin_amdgcn_mfma_f32_16x16x32_bf16(A0, B1, acc01, 0, 0, 0);
        acc10 = __builtin_amdgcn_mfma_f32_16x16x32_bf16(A1, B0, acc10, 0, 0, 0);
        acc11 = __builtin_amdgcn_mfma_f32_16x16x32_bf16(A1, B1, acc11, 0, 0, 0);
    }
    // epilogue: C/D map col=lane&15, row=half*4+reg
    int col0 = wave * 32 + m;
    int col1 = wave * 32 + 16 + m;
    float bias0 = b1[col0], bias1 = b1[col1];
#pragma unroll
    for (int reg = 0; reg < 4; reg++) {
        int r0 = row0 + half * 4 + reg;
        int r1 = r0 + 16;
        if (r0 < N_NODES) {
            h[(size_t)r0 * 128 + col0] = (unsigned short)f2bf(fmaxf(acc00[reg] + bias0, 0.f));
            h[(size_t)r0 * 128 + col1] = (unsigned short)f2bf(fmaxf(acc01[reg] + bias1, 0.f));
        }
        if (r1 < N_NODES) {
            h[(size_t)r1 * 128 + col0] = (unsigned short)f2bf(fmaxf(acc10[reg] + bias0, 0.f));
            h[(size_t)r1 * 128 + col1] = (unsigned short)f2bf(fmaxf(acc11[reg] + bias1, 0.f));
        }
    }
}

// ---------------------------------------------------------------------------
// GEMM2 (bf16 MFMA): [p|q] = h @ W2t^T; p bf16 (cols 0..63),
// q = +b2 -> out fp32 (cols 64..127).
// ---------------------------------------------------------------------------
__global__ __launch_bounds__(256) void gemm2_mfma(
    const uint4* __restrict__ h4, const uint4* __restrict__ w4,
    const float* __restrict__ b2, unsigned short* __restrict__ p,
    float* __restrict__ out)
{
    constexpr int KD = 128, KP = KD + 8;          // 136
    __shared__ unsigned short lw[128 * KP];       // 34816 B
    __shared__ unsigned short la[32 * KP];        // 8704 B
    int t = threadIdx.x;
    uint4* lw4 = (uint4*)lw;
    uint4* la4 = (uint4*)la;
    for (int i = t; i < 128 * 16; i += 256) {
        int r = i >> 4, c = i & 15;
        lw4[r * 17 + c] = w4[i];
    }
    int row0 = blockIdx.x * 32;
    for (int i = t; i < 32 * 16; i += 256) {
        int r = i >> 4, c = i & 15;
        la4[r * 17 + c] = h4[(size_t)(row0 + r) * 16 + c];
    }
    __syncthreads();

    int wave = t >> 6, lane = t & 63;
    int m = lane & 15, half = lane >> 4;
    int koff = half * 8;
    f32x4 acc00 = {}, acc01 = {}, acc10 = {}, acc11 = {};
#pragma unroll
    for (int k0 = 0; k0 < KD; k0 += 32) {
        short8 A0 = *(const short8*)&la[(m)      * KP + k0 + koff];
        short8 A1 = *(const short8*)&la[(16 + m) * KP + k0 + koff];
        short8 B0 = *(const short8*)&lw[(wave * 32 + m)      * KP + k0 + koff];
        short8 B1 = *(const short8*)&lw[(wave * 32 + 16 + m) * KP + k0 + koff];
        acc00 = __builtin_amdgcn_mfma_f32_16x16x32_bf16(A0, B0, acc00, 0, 0, 0);
        acc01 = __builtin_amdgcn_mfma_f32_16x16x32_bf16(A0, B1, acc01, 0, 0, 0);
        acc10 = __builtin_amdgcn_mfma_f32_16x16x32_bf16(A1, B0, acc10, 0, 0, 0);
        acc11 = __builtin_amdgcn_mfma_f32_16x16x32_bf16(A1, B1, acc11, 0, 0, 0);
    }
    int col0 = wave * 32 + m;
    int col1 = wave * 32 + 16 + m;
#pragma unroll
    for (int reg = 0; reg < 4; reg++) {
        int r0 = row0 + half * 4 + reg;
        int r1 = r0 + 16;
        float v00 = acc00[reg], v01 = acc01[reg];
        float v10 = acc10[reg], v11 = acc11[reg];
        if (r0 < N_NODES) {
            if (col0 < 64) p[(size_t)r0 * 64 + col0] = (unsigned short)f2bf(v00);
            else           out[(size_t)r0 * 64 + col0 - 64] = v00 + b2[col0 - 64];
            if (col1 < 64) p[(size_t)r0 * 64 + col1] = (unsigned short)f2bf(v01);
            else           out[(size_t)r0 * 64 + col1 - 64] = v01 + b2[col1 - 64];
        }
        if (r1 < N_NODES) {
            if (col0 < 64) p[(size_t)r1 * 64 + col0] = (unsigned short)f2bf(v10);
            else           out[(size_t)r1 * 64 + col0 - 64] = v10 + b2[col0 - 64];
            if (col1 < 64) p[(size_t)r1 * 64 + col1] = (unsigned short)f2bf(v11);
            else           out[(size_t)r1 * 64 + col1 - 64] = v11 + b2[col1 - 64];
        }
    }
}

// ---------------------------------------------------------------------------
// Gather 2 + finalize: out[n] += (sum_{j in N(n)} p[j]) / deg(n)
// thread = (node, 8-ch chunk c in 0..7).
// ---------------------------------------------------------------------------
__global__ __launch_bounds__(256) void gather2_kernel(
    const int* __restrict__ rowstart, const int* __restrict__ cnt,
    const int* __restrict__ adj, const uint4* __restrict__ p4,
    float* __restrict__ out)
{
    int idx = blockIdx.x * 256 + threadIdx.x;
    if (idx >= N_NODES * 8) return;
    int node = idx >> 3;
    int c = idx & 7;
    int beg = rowstart[node];
    int d = cnt[node];
    int end = beg + d;
    float a0=0,a1=0,a2=0,a3=0,a4=0,a5=0,a6=0,a7=0;
    for (int j = beg; j < end; j++) {
        int s = adj[j];
        uint4 v = p4[(size_t)s * 8 + c];
        a0 += blo(v.x); a1 += bhi(v.x);
        a2 += blo(v.y); a3 += bhi(v.y);
        a4 += blo(v.z); a5 += bhi(v.z);
        a6 += blo(v.w); a7 += bhi(v.w);
    }
    float id = 1.0f / (float)max(d, 1);
    float4* o4 = (float4*)out;
    size_t base = (size_t)node * 16 + 2 * c;
    float4 u = o4[base], v = o4[base + 1];
    u.x = fmaf(a0, id, u.x); u.y = fmaf(a1, id, u.y);
    u.z = fmaf(a2, id, u.z); u.w = fmaf(a3, id, u.w);
    v.x = fmaf(a4, id, v.x); v.y = fmaf(a5, id, v.y);
    v.z = fmaf(a6, id, v.z); v.w = fmaf(a7, id, v.w);
    o4[base] = u; o4[base + 1] = v;
}

extern "C" void kernel_launch(void* const* d_in, const int* in_sizes, int n_in,
                              void* d_out, int out_size, void* d_ws, size_t ws_size,
                              hipStream_t stream)
{
    const float* x   = (const float*)d_in[0];
    const int*   ei  = (const int*)d_in[1];
    const float* w1l = (const float*)d_in[2];
    const float* w1r = (const float*)d_in[3];
    const float* b1  = (const float*)d_in[4];
    const float* w2l = (const float*)d_in[5];
    const float* w2r = (const float*)d_in[6];
    const float* b2  = (const float*)d_in[7];
    float* out = (float*)d_out;

    int E = in_sizes[1] / 2;                  // edge_index is [2, E]
    const int* src = ei;
    const int* dst = ei + E;

    // Workspace layout. All arrays 16B-aligned by construction.
    int* cnt      = (int*)d_ws;                        // 50000
    int* rowstart = cnt + N_NODES;                     // 50000
    int* cursor   = rowstart + N_NODES;                // 50000
    int* part     = cursor + N_NODES;                  // 256
    int* partoff  = part + 256;                        // 256
    int* adj      = partoff + 256;                     // 800000
    unsigned short* xb  = (unsigned short*)(adj + E);  // 50000*96 bf16
    unsigned short* A1  = xb + (size_t)N_NODES * IN_C; // 50016*192 bf16
    unsigned short* h   = A1 + (size_t)MROWS * 192;    // 50016*128 bf16
    unsigned short* p   = h  + (size_t)MROWS * 128;    // 50000*64 bf16
    unsigned short* Wt1 = p  + (size_t)N_NODES * 64;   // 128*192 bf16
    unsigned short* Wt2 = Wt1 + 128 * 192;             // 128*128 bf16

    hipMemsetAsync(cnt, 0, N_NODES * sizeof(int), stream);

    int grid_e = (E + 255) / 256;
    hist_kernel<<<grid_e, 256, 0, stream>>>(dst, cnt, E);
    block_reduce_kernel<<<NPART, 256, 0, stream>>>(cnt, part);
    scan_partials_kernel<<<1, 256, 0, stream>>>(part, partoff);
    block_scan_kernel<<<NPART, 256, 0, stream>>>(cnt, partoff, rowstart, cursor);
    fill_kernel<<<grid_e, 256, 0, stream>>>(src, dst, cursor, adj, E);

    conv_x_kernel<<<(N_NODES * 12 + 255) / 256, 256, 0, stream>>>(
        x, (uint4*)xb, (uint4*)A1);
    conv_w1_kernel<<<(128 * 192 + 255) / 256, 256, 0, stream>>>(w1l, w1r, Wt1);
    conv_w2_kernel<<<(128 * 128 + 255) / 256, 256, 0, stream>>>(w2l, w2r, Wt2);

    gather1_kernel<<<(N_NODES * 12 + 255) / 256, 256, 0, stream>>>(
        rowstart, cnt, adj, (const uint4*)xb, (uint4*)A1);

    gemm1_mfma<<<MROWS / 32, 256, 0, stream>>>(
        (const uint4*)A1, (const uint4*)Wt1, b1, h);
    gemm2_mfma<<<MROWS / 32, 256, 0, stream>>>(
        (const uint4*)h, (const uint4*)Wt2, b2, p, out);

    gather2_kernel<<<(N_NODES * 8 + 255) / 256, 256, 0, stream>>>(
        rowstart, cnt, adj, (const uint4*)p, out);
}

// Round 4
// 222.910 us; speedup vs baseline: 8.5827x; 1.2432x over previous
//
#include <hip/hip_runtime.h>
#include <hip/hip_bf16.h>

#define N_NODES 50000
#define IN_C    96
#define HID_C   128
#define OUT_C   64
#define MROWS   50016 // 32-row-tile padded M

// CSR-build partition params
#define NB      200   // coarse buckets
#define BSZ     250   // nodes per bucket (200*250 = 50000)
#define WCHUNK  4096  // edges per workgroup in partition passes
#define NWG     196   // ceil(800000/4096)

typedef __attribute__((ext_vector_type(8))) short short8;  // 8 bf16 (4 VGPR)
typedef __attribute__((ext_vector_type(4))) float f32x4;

// round-to-nearest-even fp32 -> bf16 bits
__device__ inline unsigned int f2bf(float f) {
    unsigned int u = __float_as_uint(f);
    return (u + 0x7fffu + ((u >> 16) & 1u)) >> 16;
}
__device__ inline unsigned int pack2(float lo, float hi) {
    return f2bf(lo) | (f2bf(hi) << 16);
}
__device__ inline float blo(unsigned int u) { return __uint_as_float(u << 16); }
__device__ inline float bhi(unsigned int u) { return __uint_as_float(u & 0xffff0000u); }

// ---------------------------------------------------------------------------
// P1: per-WG coarse histogram (LDS, no global atomics).
// ---------------------------------------------------------------------------
__global__ __launch_bounds__(256) void parta_hist(
    const int* __restrict__ dst, int* __restrict__ gh, int E)
{
    __shared__ int h[NB];
    int t = threadIdx.x;
    if (t < NB) h[t] = 0;
    __syncthreads();
    int base_e = blockIdx.x * WCHUNK;
    for (int i = t; i < WCHUNK; i += 256) {
        int e = base_e + i;
        if (e < E) atomicAdd(&h[dst[e] / BSZ], 1);
    }
    __syncthreads();
    if (t < NB) gh[blockIdx.x * NB + t] = h[t];
}

// ---------------------------------------------------------------------------
// P2: bucket bases (exclusive scan of totals) + per-(WG,bucket) offsets.
// Single block; thread t owns bucket t.
// ---------------------------------------------------------------------------
__global__ __launch_bounds__(256) void parta_scan(
    const int* __restrict__ gh, int* __restrict__ ofs,
    int* __restrict__ base)
{
    __shared__ int buf[256];
    int t = threadIdx.x;
    int tot = 0;
    if (t < NB) {
        for (int w = 0; w < NWG; w++) tot += gh[w * NB + t];
    }
    buf[t] = tot;
    __syncthreads();
    for (int off = 1; off < 256; off <<= 1) {       // inclusive scan
        int v = (t >= off) ? buf[t - off] : 0;
        __syncthreads();
        buf[t] += v;
        __syncthreads();
    }
    if (t < NB) {
        int excl = buf[t] - tot;
        base[t] = excl;
        if (t == NB - 1) base[NB] = excl + tot;     // == E
        int run = excl;
        for (int w = 0; w < NWG; w++) {
            ofs[w * NB + t] = run;
            run += gh[w * NB + t];
        }
    }
}

// ---------------------------------------------------------------------------
// P3: partition edges into bucket-ordered (src,dst) pairs. Each WG's writes
// to a bucket form a contiguous run -> fully-dirty lines -> no writeback
// amplification (the round-3 fill_kernel paid 64 B/edge here).
// ---------------------------------------------------------------------------
__global__ __launch_bounds__(256) void parta_scatter(
    const int* __restrict__ src, const int* __restrict__ dst,
    const int* __restrict__ ofs, uint2* __restrict__ pairs, int E)
{
    __shared__ int cur[NB];
    int t = threadIdx.x;
    if (t < NB) cur[t] = ofs[blockIdx.x * NB + t];
    __syncthreads();
    int base_e = blockIdx.x * WCHUNK;
    for (int i = t; i < WCHUNK; i += 256) {
        int e = base_e + i;
        if (e < E) {
            int d = dst[e];
            int pos = atomicAdd(&cur[d / BSZ], 1);
            pairs[pos] = make_uint2((unsigned)src[e], (unsigned)d);
        }
    }
}

// ---------------------------------------------------------------------------
// P4: per-bucket fine CSR: LDS 250-bin histogram + scan + rank; writes
// rowstart/cnt and a contiguous adj region per bucket.
// ---------------------------------------------------------------------------
__global__ __launch_bounds__(256) void partb_csr(
    const uint2* __restrict__ pairs, const int* __restrict__ base,
    int* __restrict__ rowstart, int* __restrict__ cnt,
    int* __restrict__ adj)
{
    __shared__ int h[256];
    __shared__ int buf[256];
    __shared__ int cur[256];
    int b = blockIdx.x;
    int t = threadIdx.x;
    int beg = base[b], end = base[b + 1];
    int node0 = b * BSZ;
    h[t] = 0;
    __syncthreads();
    for (int i = beg + t; i < end; i += 256)
        atomicAdd(&h[(int)pairs[i].y - node0], 1);
    __syncthreads();
    int c = h[t];
    buf[t] = c;
    __syncthreads();
    for (int off = 1; off < 256; off <<= 1) {       // inclusive scan
        int v = (t >= off) ? buf[t - off] : 0;
        __syncthreads();
        buf[t] += v;
        __syncthreads();
    }
    int excl = buf[t] - c;
    if (t < BSZ) {
        rowstart[node0 + t] = beg + excl;
        cnt[node0 + t] = c;
    }
    cur[t] = beg + excl;
    __syncthreads();
    for (int i = beg + t; i < end; i += 256) {
        uint2 pr = pairs[i];
        int pos = atomicAdd(&cur[(int)pr.y - node0], 1);
        adj[pos] = (int)pr.x;
    }
}

// ---------------------------------------------------------------------------
// Converters (fp32 -> bf16)
// ---------------------------------------------------------------------------
__global__ __launch_bounds__(256) void conv_x_kernel(
    const float* __restrict__ x, uint4* __restrict__ xb4,
    uint4* __restrict__ a14)
{
    int idx = blockIdx.x * 256 + threadIdx.x;     // N*12
    if (idx >= N_NODES * 12) return;
    int node = idx / 12;
    int c = idx - node * 12;
    const float4* x4 = (const float4*)x;
    float4 u = x4[(size_t)node * 24 + 2 * c];
    float4 v = x4[(size_t)node * 24 + 2 * c + 1];
    uint4 w;
    w.x = pack2(u.x, u.y); w.y = pack2(u.z, u.w);
    w.z = pack2(v.x, v.y); w.w = pack2(v.z, v.w);
    xb4[(size_t)node * 12 + c] = w;
    a14[(size_t)node * 24 + 12 + c] = w;
}

// Fused weight convert: W1t[128][192] and W2t[128][128] (both col-major-T).
__global__ __launch_bounds__(256) void conv_w_kernel(
    const float* __restrict__ w1l, const float* __restrict__ w1r,
    const float* __restrict__ w2l, const float* __restrict__ w2r,
    unsigned short* __restrict__ wt1, unsigned short* __restrict__ wt2)
{
    int i = blockIdx.x * 256 + threadIdx.x;
    if (i < 128 * 192) {
        int col = i / 192, k = i - col * 192;
        float v = (k < 96) ? w1l[k * 128 + col] : w1r[(k - 96) * 128 + col];
        wt1[i] = (unsigned short)f2bf(v);
    } else {
        int j = i - 128 * 192;
        if (j < 128 * 128) {
            int col = j / 128, k = j - col * 128;
            float v = (col < 64) ? w2l[k * 64 + col] : w2r[k * 64 + col - 64];
            wt2[j] = (unsigned short)f2bf(v);
        }
    }
}

// ---------------------------------------------------------------------------
// Gather 1: A1[n][0..95] = (sum_{j in N(n)} xb[j]) / deg(n)   (bf16 out)
// ---------------------------------------------------------------------------
__global__ __launch_bounds__(256) void gather1_kernel(
    const int* __restrict__ rowstart, const int* __restrict__ cnt,
    const int* __restrict__ adj, const uint4* __restrict__ xb4,
    uint4* __restrict__ a14)
{
    int idx = blockIdx.x * 256 + threadIdx.x;
    if (idx >= N_NODES * 12) return;
    int node = idx / 12;
    int c = idx - node * 12;
    int beg = rowstart[node];
    int d = cnt[node];
    int end = beg + d;
    float a0=0,a1=0,a2=0,a3=0,a4=0,a5=0,a6=0,a7=0;
    for (int j = beg; j < end; j++) {
        int s = adj[j];
        uint4 v = xb4[(size_t)s * 12 + c];
        a0 += blo(v.x); a1 += bhi(v.x);
        a2 += blo(v.y); a3 += bhi(v.y);
        a4 += blo(v.z); a5 += bhi(v.z);
        a6 += blo(v.w); a7 += bhi(v.w);
    }
    float id = 1.0f / (float)max(d, 1);
    uint4 w;
    w.x = pack2(a0 * id, a1 * id); w.y = pack2(a2 * id, a3 * id);
    w.z = pack2(a4 * id, a5 * id); w.w = pack2(a6 * id, a7 * id);
    a14[(size_t)node * 24 + c] = w;
}

// ---------------------------------------------------------------------------
// GEMM1 (bf16 MFMA): h = relu(A1 @ W1t^T + b1)  [50000 x 128], h bf16.
// ---------------------------------------------------------------------------
__global__ __launch_bounds__(256) void gemm1_mfma(
    const uint4* __restrict__ a14, const uint4* __restrict__ w4,
    const float* __restrict__ b1, unsigned short* __restrict__ h)
{
    constexpr int KD = 192, KP = KD + 8;          // padded bf16 stride (200)
    __shared__ unsigned short lw[128 * KP];       // 51200 B
    __shared__ unsigned short la[32 * KP];        // 12800 B
    int t = threadIdx.x;
    uint4* lw4 = (uint4*)lw;
    uint4* la4 = (uint4*)la;
    for (int i = t; i < 128 * 24; i += 256) {
        int r = i / 24, c = i - r * 24;
        lw4[r * 25 + c] = w4[i];
    }
    int row0 = blockIdx.x * 32;
    for (int i = t; i < 32 * 24; i += 256) {
        int r = i / 24, c = i - r * 24;
        la4[r * 25 + c] = a14[(size_t)(row0 + r) * 24 + c];
    }
    __syncthreads();

    int wave = t >> 6, lane = t & 63;
    int m = lane & 15, half = lane >> 4;          // 0..3
    int koff = half * 8;
    f32x4 acc00 = {}, acc01 = {}, acc10 = {}, acc11 = {};
#pragma unroll
    for (int k0 = 0; k0 < KD; k0 += 32) {
        short8 A0 = *(const short8*)&la[(m)      * KP + k0 + koff];
        short8 A1 = *(const short8*)&la[(16 + m) * KP + k0 + koff];
        short8 B0 = *(const short8*)&lw[(wave * 32 + m)      * KP + k0 + koff];
        short8 B1 = *(const short8*)&lw[(wave * 32 + 16 + m) * KP + k0 + koff];
        acc00 = __builtin_amdgcn_mfma_f32_16x16x32_bf16(A0, B0, acc00, 0, 0, 0);
        acc01 = __builtin_amdgcn_mfma_f32_16x16x32_bf16(A0, B1, acc01, 0, 0, 0);
        acc10 = __builtin_amdgcn_mfma_f32_16x16x32_bf16(A1, B0, acc10, 0, 0, 0);
        acc11 = __builtin_amdgcn_mfma_f32_16x16x32_bf16(A1, B1, acc11, 0, 0, 0);
    }
    int col0 = wave * 32 + m;
    int col1 = wave * 32 + 16 + m;
    float bias0 = b1[col0], bias1 = b1[col1];
#pragma unroll
    for (int reg = 0; reg < 4; reg++) {
        int r0 = row0 + half * 4 + reg;
        int r1 = r0 + 16;
        if (r0 < N_NODES) {
            h[(size_t)r0 * 128 + col0] = (unsigned short)f2bf(fmaxf(acc00[reg] + bias0, 0.f));
            h[(size_t)r0 * 128 + col1] = (unsigned short)f2bf(fmaxf(acc01[reg] + bias1, 0.f));
        }
        if (r1 < N_NODES) {
            h[(size_t)r1 * 128 + col0] = (unsigned short)f2bf(fmaxf(acc10[reg] + bias0, 0.f));
            h[(size_t)r1 * 128 + col1] = (unsigned short)f2bf(fmaxf(acc11[reg] + bias1, 0.f));
        }
    }
}

// ---------------------------------------------------------------------------
// GEMM2 (bf16 MFMA): [p|q] = h @ W2t^T; p bf16 (cols 0..63),
// q = +b2 -> out fp32 (cols 64..127).
// ---------------------------------------------------------------------------
__global__ __launch_bounds__(256) void gemm2_mfma(
    const uint4* __restrict__ h4, const uint4* __restrict__ w4,
    const float* __restrict__ b2, unsigned short* __restrict__ p,
    float* __restrict__ out)
{
    constexpr int KD = 128, KP = KD + 8;          // 136
    __shared__ unsigned short lw[128 * KP];       // 34816 B
    __shared__ unsigned short la[32 * KP];        // 8704 B
    int t = threadIdx.x;
    uint4* lw4 = (uint4*)lw;
    uint4* la4 = (uint4*)la;
    for (int i = t; i < 128 * 16; i += 256) {
        int r = i >> 4, c = i & 15;
        lw4[r * 17 + c] = w4[i];
    }
    int row0 = blockIdx.x * 32;
    for (int i = t; i < 32 * 16; i += 256) {
        int r = i >> 4, c = i & 15;
        la4[r * 17 + c] = h4[(size_t)(row0 + r) * 16 + c];
    }
    __syncthreads();

    int wave = t >> 6, lane = t & 63;
    int m = lane & 15, half = lane >> 4;
    int koff = half * 8;
    f32x4 acc00 = {}, acc01 = {}, acc10 = {}, acc11 = {};
#pragma unroll
    for (int k0 = 0; k0 < KD; k0 += 32) {
        short8 A0 = *(const short8*)&la[(m)      * KP + k0 + koff];
        short8 A1 = *(const short8*)&la[(16 + m) * KP + k0 + koff];
        short8 B0 = *(const short8*)&lw[(wave * 32 + m)      * KP + k0 + koff];
        short8 B1 = *(const short8*)&lw[(wave * 32 + 16 + m) * KP + k0 + koff];
        acc00 = __builtin_amdgcn_mfma_f32_16x16x32_bf16(A0, B0, acc00, 0, 0, 0);
        acc01 = __builtin_amdgcn_mfma_f32_16x16x32_bf16(A0, B1, acc01, 0, 0, 0);
        acc10 = __builtin_amdgcn_mfma_f32_16x16x32_bf16(A1, B0, acc10, 0, 0, 0);
        acc11 = __builtin_amdgcn_mfma_f32_16x16x32_bf16(A1, B1, acc11, 0, 0, 0);
    }
    int col0 = wave * 32 + m;
    int col1 = wave * 32 + 16 + m;
#pragma unroll
    for (int reg = 0; reg < 4; reg++) {
        int r0 = row0 + half * 4 + reg;
        int r1 = r0 + 16;
        float v00 = acc00[reg], v01 = acc01[reg];
        float v10 = acc10[reg], v11 = acc11[reg];
        if (r0 < N_NODES) {
            if (col0 < 64) p[(size_t)r0 * 64 + col0] = (unsigned short)f2bf(v00);
            else           out[(size_t)r0 * 64 + col0 - 64] = v00 + b2[col0 - 64];
            if (col1 < 64) p[(size_t)r0 * 64 + col1] = (unsigned short)f2bf(v01);
            else           out[(size_t)r0 * 64 + col1 - 64] = v01 + b2[col1 - 64];
        }
        if (r1 < N_NODES) {
            if (col0 < 64) p[(size_t)r1 * 64 + col0] = (unsigned short)f2bf(v10);
            else           out[(size_t)r1 * 64 + col0 - 64] = v10 + b2[col0 - 64];
            if (col1 < 64) p[(size_t)r1 * 64 + col1] = (unsigned short)f2bf(v11);
            else           out[(size_t)r1 * 64 + col1 - 64] = v11 + b2[col1 - 64];
        }
    }
}

// ---------------------------------------------------------------------------
// Gather 2 + finalize: out[n] += (sum_{j in N(n)} p[j]) / deg(n)
// ---------------------------------------------------------------------------
__global__ __launch_bounds__(256) void gather2_kernel(
    const int* __restrict__ rowstart, const int* __restrict__ cnt,
    const int* __restrict__ adj, const uint4* __restrict__ p4,
    float* __restrict__ out)
{
    int idx = blockIdx.x * 256 + threadIdx.x;
    if (idx >= N_NODES * 8) return;
    int node = idx >> 3;
    int c = idx & 7;
    int beg = rowstart[node];
    int d = cnt[node];
    int end = beg + d;
    float a0=0,a1=0,a2=0,a3=0,a4=0,a5=0,a6=0,a7=0;
    for (int j = beg; j < end; j++) {
        int s = adj[j];
        uint4 v = p4[(size_t)s * 8 + c];
        a0 += blo(v.x); a1 += bhi(v.x);
        a2 += blo(v.y); a3 += bhi(v.y);
        a4 += blo(v.z); a5 += bhi(v.z);
        a6 += blo(v.w); a7 += bhi(v.w);
    }
    float id = 1.0f / (float)max(d, 1);
    float4* o4 = (float4*)out;
    size_t base = (size_t)node * 16 + 2 * c;
    float4 u = o4[base], v = o4[base + 1];
    u.x = fmaf(a0, id, u.x); u.y = fmaf(a1, id, u.y);
    u.z = fmaf(a2, id, u.z); u.w = fmaf(a3, id, u.w);
    v.x = fmaf(a4, id, v.x); v.y = fmaf(a5, id, v.y);
    v.z = fmaf(a6, id, v.z); v.w = fmaf(a7, id, v.w);
    o4[base] = u; o4[base + 1] = v;
}

extern "C" void kernel_launch(void* const* d_in, const int* in_sizes, int n_in,
                              void* d_out, int out_size, void* d_ws, size_t ws_size,
                              hipStream_t stream)
{
    const float* x   = (const float*)d_in[0];
    const int*   ei  = (const int*)d_in[1];
    const float* w1l = (const float*)d_in[2];
    const float* w1r = (const float*)d_in[3];
    const float* b1  = (const float*)d_in[4];
    const float* w2l = (const float*)d_in[5];
    const float* w2r = (const float*)d_in[6];
    const float* b2  = (const float*)d_in[7];
    float* out = (float*)d_out;

    int E = in_sizes[1] / 2;                  // edge_index is [2, E]
    const int* src = ei;
    const int* dst = ei + E;

    // Workspace layout (4B units, every array size a multiple of 16 B).
    int* gh       = (int*)d_ws;                        // 196*200 = 39200
    int* ofs      = gh + NWG * NB;                     // 39200
    int* base     = ofs + NWG * NB;                    // 256 (NB+1 used)
    int* cnt      = base + 256;                        // 50000
    int* rowstart = cnt + N_NODES;                     // 50000
    uint2* pairs  = (uint2*)(rowstart + N_NODES);      // 800000 uint2
    int* adj      = (int*)(pairs + 800000);            // 800000
    unsigned short* xb  = (unsigned short*)(adj + 800000); // 50000*96 bf16
    unsigned short* A1  = xb + (size_t)N_NODES * IN_C; // 50016*192 bf16
    unsigned short* h   = A1 + (size_t)MROWS * 192;    // 50016*128 bf16
    unsigned short* p   = h  + (size_t)MROWS * 128;    // 50000*64 bf16
    unsigned short* Wt1 = p  + (size_t)N_NODES * 64;   // 128*192 bf16
    unsigned short* Wt2 = Wt1 + 128 * 192;             // 128*128 bf16

    // CSR build (locality-aware two-pass counting sort; no memset needed)
    parta_hist<<<NWG, 256, 0, stream>>>(dst, gh, E);
    parta_scan<<<1, 256, 0, stream>>>(gh, ofs, base);
    parta_scatter<<<NWG, 256, 0, stream>>>(src, dst, ofs, pairs, E);
    partb_csr<<<NB, 256, 0, stream>>>(pairs, base, rowstart, cnt, adj);

    conv_x_kernel<<<(N_NODES * 12 + 255) / 256, 256, 0, stream>>>(
        x, (uint4*)xb, (uint4*)A1);
    conv_w_kernel<<<(128 * 192 + 128 * 128 + 255) / 256, 256, 0, stream>>>(
        w1l, w1r, w2l, w2r, Wt1, Wt2);

    gather1_kernel<<<(N_NODES * 12 + 255) / 256, 256, 0, stream>>>(
        rowstart, cnt, adj, (const uint4*)xb, (uint4*)A1);

    gemm1_mfma<<<MROWS / 32, 256, 0, stream>>>(
        (const uint4*)A1, (const uint4*)Wt1, b1, h);
    gemm2_mfma<<<MROWS / 32, 256, 0, stream>>>(
        (const uint4*)h, (const uint4*)Wt2, b2, p, out);

    gather2_kernel<<<(N_NODES * 8 + 255) / 256, 256, 0, stream>>>(
        rowstart, cnt, adj, (const uint4*)p, out);
}